// Round 9
// baseline (112.537 us; speedup 1.0000x reference)
//
#include <hip/hip_runtime.h>

// CRITICAL: hipcc defaults to -ffp-contract=fast-honor-pragmas, and HIP's
// __fmul_rn/__fadd_rn are PLAIN OPERATORS (not contraction barriers like
// CUDA). This pragma guarantees mul/add are not fused into v_fmac/v_pk_fma,
// so our rounding matches numpy's exactly. (R4 proved this: absmax == 0.0.)
#pragma clang fp contract(off)

// HISTORY of falsified theories (all flat at ~58-61 µs):
//  R12 PP=8->4 (remat), R13 BLK=1024 (occupancy), R14 scalar-C (SLP repack,
//  non-discriminating), R15 register prefetch (exposed LDS latency),
//  R16 asm-pinned scalar (pk=8cyc theory dead; VALUBusy>100% proved the
//  derived counter is instr-count*4/elapsed, not pipe saturation).
//  Decisive: wall = 281 cyc/SIMD/wave-iter for BOTH 42-instr and 74-instr
//  loops => VALU acquitted. Never varied until now: the LDS stream.
//  CC=32 made lanes 32-63 re-read lanes 0-31's key pairs: 2x ds_read_b128
//  per wave-iter x 64 iters, half the bytes duplicated, 16 phase-locked
//  waves/CU convoying through the per-CU LDS unit every iteration.
//  R17: CC=64 — each lane owns pair j=64k+l; 32 iters, all-distinct b128s.
//  ds_read instruction count HALVES; per-iter convoy stalls halve.
static __device__ __forceinline__ float smul(float a, float b) {
    float d;
    asm("v_mul_f32 %0, %1, %2" : "=v"(d) : "v"(a), "v"(b));
    return d;
}
static __device__ __forceinline__ float sadd(float a, float b) {
    float d;
    asm("v_add_f32 %0, %1, %2" : "=v"(d) : "v"(a), "v"(b));
    return d;
}
static __device__ __forceinline__ float min3f(float a, float b, float c) {
    float d;
    asm("v_min3_f32 %0, %1, %2, %3" : "=v"(d) : "v"(a), "v"(b), "v"(c));
    return d;
}

// Problem constants (from reference): B=4, N=16384, M=4096, D=64
#define MM 4096
#define DD 64
#define BN 65536                  // B*N points
#define FEATS_OFF 0               // feats: BN*DD floats
#define IDS_OFF (BN * DD)         // ids:   BN floats (ints stored as float)
#define PC_OFF (IDS_OFF + BN)     // pc:    BN*3 floats passthrough

#define BLK 512                   // threads per block (8 waves)
#define PP 8                      // points per thread (= per wave; scalar regs)
#define PPB 64                    // points per block (8 waves x 8 points)
#define NPAIR (MM / 2)            // 2048 key pairs
#define KIT (MM / (2 * 64))       // 32 main-loop iterations (64 pairs/iter)

// NUMERICS (bit-exact vs numpy fp32 replay — verified R4-R8, R14, R16):
//  - keys stored NEGATED+DOUBLED: rn commutes with sign and 2^k scaling, so
//    cross' = ((px*(-2kx) + py*(-2ky)) + pz*(-2kz)) == -2*cross bit-exact,
//    and d2 = (psq + cross') + ksq == (psq - 2*cross) + ksq == ref bits.
//  - all plain rn (contract off); asm v_mul/v_add are rn; association order
//    identical to the verified R14/R16 scalar expression (absmax 0.0).
//    FMA / dropping psq / MFMA are FORBIDDEN: each changes rounding; a
//    rounding-created tie flips argmin's first-index rule.
//  - argmin (semantics unchanged, id map re-derived for CC=64):
//    lane l, iter k owns keys 2(64k+l), 2(64k+l)+1. bd via v_min3
//    (== sequential strict-'<' min, no NaNs); bk = first iter where bd
//    strictly dropped (later equal values don't overwrite => within-lane
//    first-index kept, and ids grow with k); within-pair even preferred on
//    tie at recovery; 6-step lexicographic (d2,id) butterfly across the
//    full wave64 picks the smallest id among global-min holders
//    == global first-index argmin.
__global__ __launch_bounds__(BLK) __attribute__((amdgpu_waves_per_eu(4, 4)))
void quant_embed_kernel(const float* __restrict__ pc,
                        const float* __restrict__ keys,
                        const float* __restrict__ values,
                        float* __restrict__ out)
{
#pragma clang fp contract(off)
    __shared__ float4 skA[NPAIR];  // (-2kx_e, -2kx_o, -2ky_e, -2ky_o) 32 KiB
    __shared__ float4 skB[NPAIR];  // (-2kz_e, -2kz_o,  ksq_e,  ksq_o) 32 KiB

    const int tid = threadIdx.x;

    // Stage key pairs: pair j = keys 2j (f0.x,f0.y,f1.x), 2j+1 (f1.y,f2.x,f2.y).
    #pragma unroll
    for (int i = 0; i < NPAIR / BLK; ++i) {
        const int j = tid + i * BLK;
        const float2 f0 = ((const float2*)keys)[3 * j + 0];
        const float2 f1 = ((const float2*)keys)[3 * j + 1];
        const float2 f2 = ((const float2*)keys)[3 * j + 2];
        const float ksq0 = ((f0.x * f0.x) + (f0.y * f0.y)) + (f1.x * f1.x);
        const float ksq1 = ((f1.y * f1.y) + (f2.x * f2.x)) + (f2.y * f2.y);
        skA[j] = make_float4(-2.0f * f0.x, -2.0f * f1.y,
                             -2.0f * f0.y, -2.0f * f2.x);
        skB[j] = make_float4(-2.0f * f1.x, -2.0f * f2.y, ksq0, ksq1);
    }

    // pc passthrough for this block's 64 points: 192 floats = 48 float4.
    {
        const int base = blockIdx.x * (PPB * 3 / 4);  // in float4
        if (tid < PPB * 3 / 4) {
            ((float4*)(out + PC_OFF))[base + tid] =
                ((const float4*)pc)[base + tid];
        }
    }

    const int l = tid & 63;                       // lane in wave
    const int g = tid >> 6;                       // wave id 0..7
    const int p0 = blockIdx.x * PPB + g * PP;     // my wave's first point

    // Load my wave's 8 points (24 floats = 6 float4; wave-uniform addresses,
    // L1 broadcast). 3*p0 % 4 == 0 keeps float4 alignment.
    float arr[24];
    {
        const float4* pcv = (const float4*)(pc + 3 * p0);
        #pragma unroll
        for (int i = 0; i < 6; ++i) ((float4*)arr)[i] = pcv[i];
    }
    float PX[PP], PY[PP], PZ[PP], PSQ[PP];
    float bd[PP];
    int bk[PP];
    #pragma unroll
    for (int i = 0; i < PP; ++i) {
        PX[i] = arr[3 * i + 0];
        PY[i] = arr[3 * i + 1];
        PZ[i] = arr[3 * i + 2];
        PSQ[i] = ((PX[i] * PX[i]) + (PY[i] * PY[i])) + (PZ[i] * PZ[i]);
        bd[i] = 3.402823466e38f;
        bk[i] = 0;
    }

    __syncthreads();

    // Main loop: lane l, iter k handles pair j = 64k + l (keys 128k+2l, +1).
    // 32 iters; 2 ds_read_b128 per wave-iter, all 64 addresses distinct.
    #pragma unroll 2
    for (int k = 0; k < KIT; ++k) {
        const int j = (k << 6) + l;
        const float4 A  = skA[j];   // (-2kx_e, -2kx_o, -2ky_e, -2ky_o)
        const float4 Bv = skB[j];   // (-2kz_e, -2kz_o,  ksq_e,  ksq_o)
        #pragma unroll
        for (int i = 0; i < PP; ++i) {
            // even key: ((px*kx + py*ky) + pz*kz); (psq + t) + ksq
            const float e0 = smul(PX[i], A.x);
            const float e1 = smul(PY[i], A.z);
            const float e2 = sadd(e0, e1);
            const float e3 = smul(PZ[i], Bv.x);
            const float e4 = sadd(e2, e3);
            const float e5 = sadd(PSQ[i], e4);
            const float d0 = sadd(e5, Bv.z);
            // odd key
            const float o0 = smul(PX[i], A.y);
            const float o1 = smul(PY[i], A.w);
            const float o2 = sadd(o0, o1);
            const float o3 = smul(PZ[i], Bv.y);
            const float o4 = sadd(o2, o3);
            const float o5 = sadd(PSQ[i], o4);
            const float d1 = sadd(o5, Bv.w);
            const float nb = min3f(bd[i], d0, d1);
            const bool ch = nb < bd[i];  // strict drop => first-index kept
            bd[i] = nb;
            bk[i] = ch ? k : bk[i];
        }
    }

    // Recover the winning key within pair bk[i] (same rn scalar expression),
    // then merge all 64 lanes (lexicographic (d2,id) butterfly, 6 steps).
    int bm[PP];
    #pragma unroll
    for (int i = 0; i < PP; ++i) {
        const int j = (bk[i] << 6) + l;
        const float4 A  = skA[j];
        const float4 Bv = skB[j];
        const float ca = ((PX[i] * A.x) + (PY[i] * A.z)) + (PZ[i] * Bv.x);
        const float da = (PSQ[i] + ca) + Bv.z;
        const int m0 = (bk[i] << 7) + (l << 1);
        float d = bd[i];
        int   m = (da == bd[i]) ? m0 : (m0 + 1);  // even preferred on tie
        #pragma unroll
        for (int off = 1; off < 64; off <<= 1) {
            const float od = __shfl_xor(d, off);
            const int   om = __shfl_xor(m, off);
            if (od < d || (od == d && om < m)) { d = od; m = om; }
        }
        bm[i] = m;
    }

    // Epilogue: each point's 64 lanes copy its 64-float value row
    // (1 float per lane, coalesced 256B); lane 0 writes the id.
    #pragma unroll
    for (int i = 0; i < PP; ++i) {
        const float* vrow = values + (size_t)bm[i] * DD;
        out[FEATS_OFF + (size_t)(p0 + i) * DD + l] = vrow[l];
        if (l == 0) out[IDS_OFF + p0 + i] = (float)bm[i];
    }
}

extern "C" void kernel_launch(void* const* d_in, const int* in_sizes, int n_in,
                              void* d_out, int out_size, void* d_ws, size_t ws_size,
                              hipStream_t stream) {
    const float* pc     = (const float*)d_in[0];
    const float* keys   = (const float*)d_in[1];
    const float* values = (const float*)d_in[2];
    float* out = (float*)d_out;

    dim3 grid(BN / PPB);  // 1024 blocks of 512 threads (2 resident/CU)
    dim3 block(BLK);
    quant_embed_kernel<<<grid, block, 0, stream>>>(pc, keys, values, out);
}